// Round 10
// baseline (2395.348 us; speedup 1.0000x reference)
//
#include <hip/hip_runtime.h>
#include <math.h>

// B=512, N=128, E=256, H=8, D=32. All fp32 (argmax fidelity requires it).
//
// Round-10: live within the measured VGPR law (65536/block_size).
//  State partition per batch element: V in LDS (135KB, padded), L in registers
//  (64 floats/thread @512thr -> fits the 128-VGPR budget), K streamed from ws
//  every step (loop-invariant addresses; per-XCD working set ~4MB ~= L2).
//  sq' = qbase + emb@WstepBot precomputed into ws (takes v's old slot; proven
//  202.4MB footprint). V computed by an in-kernel init GEMM. 4 barriers/step.

#define B_ 512
#define N_ 128
#define E_ 256
#define NEG (-1.0e9f)
#define CLIPV 10.0f
#define SCALE 0.17677669529663688110f  /* 1/sqrt(32), fp32-rounded */

#define REP8(M) M(0) M(1) M(2) M(3) M(4) M(5) M(6) M(7)
#define REP16(M) REP8(M) M(8) M(9) M(10) M(11) M(12) M(13) M(14) M(15)
#define DOT4(a,b) ((a).x*(b).x + (a).y*(b).y + (a).z*(b).z + (a).w*(b).w)

__device__ __forceinline__ void fma4(float4& d, float a, float4 b) {
  d.x += a * b.x; d.y += a * b.y; d.z += a * b.z; d.w += a * b.w;
}
__device__ __forceinline__ float4 add4(float4 a, float4 b) {
  return make_float4(a.x + b.x, a.y + b.y, a.z + b.z, a.w + b.w);
}

// ---------------- wave-wide reductions (64 lanes) ----------------
template <int CTRL>
__device__ __forceinline__ float dpp_f(float x) {
  int r = __builtin_amdgcn_update_dpp(__float_as_int(x), __float_as_int(x),
                                      CTRL, 0xf, 0xf, false);
  return __int_as_float(r);
}
__device__ __forceinline__ float wred_max(float v) {
  v = fmaxf(v, dpp_f<0xB1>(v));
  v = fmaxf(v, dpp_f<0x4E>(v));
  v = fmaxf(v, dpp_f<0x124>(v));
  v = fmaxf(v, dpp_f<0x128>(v));
  v = fmaxf(v, __shfl_xor(v, 16));
  v = fmaxf(v, __shfl_xor(v, 32));
  return v;
}
__device__ __forceinline__ float wred_sum(float v) {
  v += dpp_f<0xB1>(v);
  v += dpp_f<0x4E>(v);
  v += dpp_f<0x124>(v);
  v += dpp_f<0x128>(v);
  v += __shfl_xor(v, 16);
  v += __shfl_xor(v, 32);
  return v;
}

// ---------------------------------------------------------------- K0: weight folds
__global__ void k0_prep(const float* __restrict__ Wqkv, const float* __restrict__ bqkv,
                        const float* __restrict__ Wmlp, const float* __restrict__ bmlp,
                        float* __restrict__ Wc, float* __restrict__ bc,
                        float* __restrict__ wc2, float* __restrict__ cconst) {
  int t = threadIdx.x;
  int blk = blockIdx.x;
  __shared__ float row_s[E_];
  if (blk < E_) {
    int g = blk;
    row_s[t] = Wqkv[g * 768 + 512 + t];
    __syncthreads();
    int f = t;
    const float4* wm4 = (const float4*)(Wmlp + f * E_);
    const float4* w34 = (const float4*)row_s;
    float acc = 0.f;
#pragma unroll 8
    for (int j = 0; j < E_ / 4; ++j) {
      float4 a = w34[j]; float4 bv = wm4[j];
      acc += a.x * bv.x + a.y * bv.y + a.z * bv.z + a.w * bv.w;
    }
    Wc[g * E_ + f] = acc;
  } else {
    int f = t;
    float a1 = 0.f, a2 = 0.f;
    for (int e = 0; e < E_; ++e) {
      a1 += bqkv[512 + e] * Wmlp[f * E_ + e];
      a2 += Wqkv[f * 768 + 512 + e] * bmlp[e];
    }
    bc[f] = a1;
    wc2[f] = a2;
    if (t == 0) {
      float c = 0.f;
      for (int e = 0; e < E_; ++e) c += bqkv[512 + e] * bmlp[e];
      *cconst = c;
    }
  }
}

// ---------------------------------------------------------------- K1: precompute GEMM
// 3 tensors, all stored PLAIN [row][col] (coalesced stores):
//  cc>>1 == 0: k   = emb@Wqkv[:,0:256]   + bqkv[0:256]
//  cc>>1 == 1: sq' = emb@Wstep[256:512,] + qbase[b]      (row-dependent add)
//  cc>>1 == 2: lk2 = emb@Wc + bc
__global__ __launch_bounds__(256, 2)
void k_gemm(const float* __restrict__ emb, const float* __restrict__ Wqkv,
            const float* __restrict__ bqkv, const float* __restrict__ Wstep,
            const float* __restrict__ Wc, const float* __restrict__ bc,
            const float* __restrict__ qbase,
            float* __restrict__ kk_, float* __restrict__ sqp,
            float* __restrict__ lkp) {
  __shared__ float As[256 * 64];  // [kk][m], exactly 64 KiB
  int t = threadIdx.x;
  int r0 = blockIdx.x * 64;
  {
    int m = t >> 2;
    int c0 = t & 3;
    const float4* e4 = (const float4*)emb;
#pragma unroll
    for (int p = 0; p < 16; ++p) {
      int c4 = c0 + p * 4;
      float4 a = e4[(size_t)(r0 + m) * 64 + c4];
      As[(c4 * 4 + 0) * 64 + m] = a.x;
      As[(c4 * 4 + 1) * 64 + m] = a.y;
      As[(c4 * 4 + 2) * 64 + m] = a.z;
      As[(c4 * 4 + 3) * 64 + m] = a.w;
    }
  }
  __syncthreads();
  int tx = t & 15, ty = t >> 4;
  const float4* As4 = (const float4*)As;
  for (int cc = 0; cc < 6; ++cc) {
    const float* Bp; int ldb4; const float* bias; float* outp; const float* qa;
    int colbase = (cc & 1) * 128;
    switch (cc >> 1) {
      case 0:  Bp = Wqkv + colbase;          ldb4 = 192; bias = bqkv + colbase; outp = kk_; qa = nullptr; break;
      case 1:  Bp = Wstep + 65536 + colbase; ldb4 = 64;  bias = nullptr;        outp = sqp; qa = qbase;  break;
      default: Bp = Wc + colbase;            ldb4 = 64;  bias = bc + colbase;   outp = lkp; qa = nullptr; break;
    }
    const float4* B4 = (const float4*)Bp;
    float acc[4][8];
#pragma unroll
    for (int i = 0; i < 4; ++i)
#pragma unroll
      for (int j = 0; j < 8; ++j) acc[i][j] = 0.f;

#pragma unroll 4
    for (int kk = 0; kk < 256; ++kk) {
      float4 b0 = B4[kk * ldb4 + tx * 2];
      float4 b1 = B4[kk * ldb4 + tx * 2 + 1];
      float4 av = As4[kk * 16 + ty];
      float a_[4] = {av.x, av.y, av.z, av.w};
#pragma unroll
      for (int i = 0; i < 4; ++i) {
        acc[i][0] += a_[i] * b0.x; acc[i][1] += a_[i] * b0.y;
        acc[i][2] += a_[i] * b0.z; acc[i][3] += a_[i] * b0.w;
        acc[i][4] += a_[i] * b1.x; acc[i][5] += a_[i] * b1.y;
        acc[i][6] += a_[i] * b1.z; acc[i][7] += a_[i] * b1.w;
      }
    }
    float bj[8];
#pragma unroll
    for (int j = 0; j < 8; ++j) bj[j] = bias ? bias[tx * 8 + j] : 0.f;
#pragma unroll
    for (int i = 0; i < 4; ++i) {
      int row = r0 + ty * 4 + i;
      float4 o0 = make_float4(acc[i][0] + bj[0], acc[i][1] + bj[1], acc[i][2] + bj[2], acc[i][3] + bj[3]);
      float4 o1 = make_float4(acc[i][4] + bj[4], acc[i][5] + bj[5], acc[i][6] + bj[6], acc[i][7] + bj[7]);
      if (qa) {
        int bb = row >> 7;
        const float4* q4p = (const float4*)(qa + bb * 256 + colbase + tx * 8);
        o0 = add4(o0, q4p[0]); o1 = add4(o1, q4p[1]);
      }
      float4* o4 = (float4*)(outp + (size_t)row * 256 + colbase + tx * 8);
      o4[0] = o0; o4[1] = o1;
    }
  }
}

// ---------------------------------------------------------------- K2: qbase per b
__global__ void k_qbase(const float* __restrict__ emb, const float* __restrict__ Wfix,
                        const float* __restrict__ bfix, const float* __restrict__ Wstep,
                        const float* __restrict__ bstep, float* __restrict__ qbase) {
  int b = blockIdx.x, t = threadIdx.x;
  __shared__ float ge[E_], fi[E_];
  const float* eb = emb + (size_t)b * N_ * E_;
  float s = 0.f;
#pragma unroll 8
  for (int n = 0; n < N_; ++n) s += eb[n * E_ + t];
  ge[t] = s * (1.0f / 128.0f);
  fi[t] = eb[t];
  __syncthreads();
  float acc = bfix[t] + bstep[t];
#pragma unroll 4
  for (int g = 0; g < E_; ++g)
    acc += ge[g] * Wfix[g * E_ + t] + fi[g] * Wstep[g * E_ + t];
  qbase[b * E_ + t] = acc;
}

// ---------------------------------------------------------------- K3: c[b,n]
__global__ void k_c(const float* __restrict__ emb, const float* __restrict__ wc2,
                    const float* __restrict__ cconst, float* __restrict__ cvec) {
  __shared__ float w[E_];
  int t = threadIdx.x;
  w[t] = wc2[t];
  __syncthreads();
  int row = blockIdx.x * 256 + t;
  const float4* e4 = (const float4*)(emb + (size_t)row * E_);
  const float4* w4 = (const float4*)w;
  float acc = 0.f;
#pragma unroll 8
  for (int j = 0; j < E_ / 4; ++j) {
    float4 a = e4[j], bv = w4[j];
    acc += a.x * bv.x + a.y * bv.y + a.z * bv.z + a.w * bv.w;
  }
  cvec[row] = acc + *cconst;
}

// ---------------------------------------------------------------- K4: rollout
// 512 thr, 1 b/block. V in LDS (VT[e][n], stride 132), L in regs (pinned),
// K + sq' streamed from ws each step. 4 barriers/step.
__global__ __launch_bounds__(512)
void k_roll(const float* __restrict__ emb, const float* __restrict__ Wqkv,
            const float* __restrict__ bqkv,
            const float* __restrict__ kk, const float* __restrict__ sqp,
            const float* __restrict__ lkp,
            const float* __restrict__ cvec, float* __restrict__ out) {
  int lt = threadIdx.x;
  int b = blockIdx.x;
  int w = lt >> 6;      // wave (== head for softmax/ctx)
  int j = lt & 63;      // lane

  __shared__ float VT[256 * 132];       // 135,168 B
  __shared__ float work[6144];          // 24 KiB overlay (init staging / step bufs)
  __shared__ int vis[128];
  float* q_s   = work;                  // 256
  float* sc_s  = work + 256;            // [8][128]
  float* at_s  = work + 1280;           // [8][128]
  float* ctx_s = work + 2304;           // [256]
  float* zp    = work + 2560;           // [4][128]

  if (lt < 128) vis[lt] = (lt == 0) ? 1 : 0;

  // ---- init: V = emb@Wqkv[:,256:512] + bqkv[256:512] -> VT[e][n] in LDS ----
  {
    float* At = work;           // [16][128]
    float* Bs = work + 2048;    // [16][256]
    const float4* eb4 = (const float4*)(emb + (size_t)b * 32768);
    const float4* wq4 = (const float4*)Wqkv;   // row stride 192 float4
    int n0 = (lt & 31) * 4;
    int e0 = (lt >> 5) * 16;
    float4 z4 = make_float4(0.f, 0.f, 0.f, 0.f);
#define DECAC(i) float4 ac##i##_0=z4, ac##i##_1=z4, ac##i##_2=z4, ac##i##_3=z4;
    DECAC(0) DECAC(1) DECAC(2) DECAC(3)

    for (int gc = 0; gc < 16; ++gc) {
      {
        int n = lt & 127, q4g = lt >> 7;
        float4 a = eb4[n * 64 + gc * 4 + q4g];
        At[(q4g * 4 + 0) * 128 + n] = a.x;
        At[(q4g * 4 + 1) * 128 + n] = a.y;
        At[(q4g * 4 + 2) * 128 + n] = a.z;
        At[(q4g * 4 + 3) * 128 + n] = a.w;
      }
      {
        int i1 = lt, i2 = lt + 512;
        ((float4*)Bs)[i1] = wq4[(gc * 16 + (i1 >> 6)) * 192 + 64 + (i1 & 63)];
        ((float4*)Bs)[i2] = wq4[(gc * 16 + (i2 >> 6)) * 192 + 64 + (i2 & 63)];
      }
      __syncthreads();
#pragma unroll
      for (int gi = 0; gi < 16; ++gi) {
        float4 a4v = *(const float4*)(At + gi * 128 + n0);
        const float4* bp = (const float4*)(Bs + gi * 256 + e0);
        float4 b0 = bp[0], b1 = bp[1], b2 = bp[2], b3 = bp[3];
#define ACU(i, comp) fma4(ac##i##_0, a4v.comp, b0); fma4(ac##i##_1, a4v.comp, b1); \
                     fma4(ac##i##_2, a4v.comp, b2); fma4(ac##i##_3, a4v.comp, b3);
        ACU(0, x) ACU(1, y) ACU(2, z) ACU(3, w)
      }
      __syncthreads();
    }
    const float* bv = bqkv + 256;
#define STOV(i, g) { float4 a = ac##i##_##g; \
    float4 bvv = *(const float4*)(bv + e0 + (g) * 4); \
    VT[(e0 + (g)*4 + 0) * 132 + n0 + (i)] = a.x + bvv.x; \
    VT[(e0 + (g)*4 + 1) * 132 + n0 + (i)] = a.y + bvv.y; \
    VT[(e0 + (g)*4 + 2) * 132 + n0 + (i)] = a.z + bvv.z; \
    VT[(e0 + (g)*4 + 3) * 132 + n0 + (i)] = a.w + bvv.w; }
    STOV(0,0) STOV(0,1) STOV(0,2) STOV(0,3)
    STOV(1,0) STOV(1,1) STOV(1,2) STOV(1,3)
    STOV(2,0) STOV(2,1) STOV(2,2) STOV(2,3)
    STOV(3,0) STOV(3,1) STOV(3,2) STOV(3,3)
  }

  // ---- L register fill (64 floats, pinned resident) ----
  int zn = lt & 127, zeq = lt >> 7;     // z phase: node, e-quarter
  const float4* lq4 = (const float4*)(lkp + (size_t)b * 32768) + zn * 64 + zeq * 16;
#define LDL(i) float4 L_##i = lq4[(i)];
  REP16(LDL)
#define PIN4(v) asm volatile("" : "+v"((v).x), "+v"((v).y), "+v"((v).z), "+v"((v).w));
#define PINL(i) PIN4(L_##i)
  REP16(PINL)

  // score phase mapping
  int sn = lt >> 2, sq_ = lt & 3;       // node, e-quarter (heads 2q, 2q+1)
  const float4* kb4 = (const float4*)(kk + (size_t)b * 32768);
  const float* sqrow = sqp + (size_t)b * 32768;

  // ctx phase mapping
  int epair = j >> 1, nh = j & 1;
  int e_c = w * 32 + epair;

  float cv_lo = cvec[b * 128 + j];
  float cv_hi = cvec[b * 128 + j + 64];
  int vis_lo = (j == 0) ? 1 : 0, vis_hi = 0;
  int cur = 0;
  float lp = 0.f;
  __syncthreads();

#pragma unroll 1
  for (int it = 0; it < N_ - 1; ++it) {
    // --- P0: stage q row (sq' has qbase folded) ---
    if (lt < 256) q_s[lt] = sqrow[cur * 256 + lt];
    __syncthreads();                                   // B1

    // --- P1: scores. K streamed (addresses static; asm off defeats hoisting) ---
    {
      int off = 0;
      asm volatile("" : "+v"(off));
      const float4* kp = kb4 + sn * 64 + sq_ * 16 + off;
      const float4* qp = (const float4*)q_s + sq_ * 16;
#define LDKA(i) float4 KA_##i = kp[(i)];
#define LDKB(i) float4 KB_##i = kp[8 + (i)];
      REP8(LDKA) REP8(LDKB)
      float s0a = 0.f, s0b = 0.f, s1a = 0.f, s1b = 0.f;
#define DOTA(i) { float4 qv = qp[(i)]; \
      if ((i) & 1) s0b += DOT4(qv, KA_##i); else s0a += DOT4(qv, KA_##i); }
#define DOTB(i) { float4 qv = qp[8 + (i)]; \
      if ((i) & 1) s1b += DOT4(qv, KB_##i); else s1a += DOT4(qv, KB_##i); }
      REP8(DOTA) REP8(DOTB)
      int vn = vis[sn];
      sc_s[(sq_ * 2) * 128 + sn]     = vn ? NEG : (s0a + s0b) * SCALE;
      sc_s[(sq_ * 2 + 1) * 128 + sn] = vn ? NEG : (s1a + s1b) * SCALE;
    }
    __syncthreads();                                   // B2

    // --- P2: softmax (wave == head); inv stays in-register for P3 ---
    float inv;
    {
      float s0 = sc_s[w * 128 + j], s1 = sc_s[w * 128 + 64 + j];
      float m = wred_max(fmaxf(s0, s1));
      float e0 = expf(s0 - m), e1 = expf(s1 - m);
      at_s[w * 128 + j] = e0;
      at_s[w * 128 + 64 + j] = e1;
      inv = 1.0f / wred_sum(e0 + e1);
    }
    // --- P3: ctx (wave-local: at_s[w] written by this wave; no barrier) ---
    {
      const float4* a4 = (const float4*)(at_s + w * 128 + nh * 64);
      const float4* v4 = (const float4*)(VT + e_c * 132 + nh * 64);
      float c0 = 0.f, c1 = 0.f;
#define CTM(i) { float4 av = a4[(i)]; float4 vv = v4[(i)]; \
      if ((i) & 1) c1 += DOT4(av, vv); else c0 += DOT4(av, vv); }
      REP16(CTM)
      float c = c0 + c1;
      c += __shfl_xor(c, 1);      // combine n-halves (lane pairs share e_c)
      c *= inv;
      if (nh == 0) ctx_s[e_c] = c;
    }
    __syncthreads();                                   // B3

    // --- P4: z partial (ctx broadcast; L from registers) ---
    {
      const float4* cx4 = (const float4*)(ctx_s + zeq * 64);
      float z0 = 0.f, z1 = 0.f;
#define ZPM(i) { float4 cv = cx4[(i)]; \
      if ((i) & 1) z1 += DOT4(cv, L_##i); else z0 += DOT4(cv, L_##i); }
      REP16(ZPM)
      zp[zeq * 128 + zn] = z0 + z1;
    }
    __syncthreads();                                   // B4

    // --- P5: phase C, redundantly per wave (identical inputs -> same action) ---
    {
      float zlo = cv_lo + ((zp[j] + zp[128 + j]) + (zp[256 + j] + zp[384 + j]));
      float zhi = cv_hi + ((zp[64 + j] + zp[192 + j]) + (zp[320 + j] + zp[448 + j]));
      float zmlo = vis_lo ? -1e30f : zlo;
      float zmhi = vis_hi ? -1e30f : zhi;
      float vmax = wred_max(fmaxf(zmlo, zmhi));
      unsigned long long blo = __ballot(zmlo == vmax);
      int action;
      if (blo) action = __ffsll(blo) - 1;
      else     action = 63 + __ffsll((unsigned long long)__ballot(zmhi == vmax));
      float lmax = CLIPV * tanhf(vmax * SCALE);
      float tlo = vis_lo ? 0.f : expf(CLIPV * tanhf(zlo * SCALE) - 10.0f);
      float thi = vis_hi ? 0.f : expf(CLIPV * tanhf(zhi * SCALE) - 10.0f);
      float S = wred_sum(tlo + thi);
      lp += lmax - 10.0f - logf(S);
      cur = action;
      vis_lo |= (action == j);
      vis_hi |= (action == j + 64);
      if (lt == action) vis[action] = 1;
    }
  }
  if (lt == 0) out[b] = lp;
}

// ---------------------------------------------------------------- launch
extern "C" void kernel_launch(void* const* d_in, const int* in_sizes, int n_in,
                              void* d_out, int out_size, void* d_ws, size_t ws_size,
                              hipStream_t stream) {
  (void)in_sizes; (void)n_in; (void)out_size; (void)ws_size;
  const float* emb   = (const float*)d_in[0];
  const float* Wqkv  = (const float*)d_in[1];
  const float* bqkv  = (const float*)d_in[2];
  const float* Wfix  = (const float*)d_in[3];
  const float* bfix  = (const float*)d_in[4];
  const float* Wstep = (const float*)d_in[5];
  const float* bstep = (const float*)d_in[6];
  const float* Wmlp  = (const float*)d_in[7];
  const float* bmlp  = (const float*)d_in[8];
  float* out = (float*)d_out;
  float* ws = (float*)d_ws;

  const size_t NBE = (size_t)B_ * N_ * E_;  // 16,777,216 floats
  float* kk_    = ws;                  // k   [b][n][e]
  float* sqp    = ws + NBE;            // sq' [b][n][e]  (qbase folded in)
  float* lkp    = ws + 2 * NBE;        // lk2 [b][n][e]
  float* qbase  = ws + 3 * NBE;        // 131072
  float* cvec   = qbase + 131072;      // 65536
  float* Wc     = cvec + 65536;        // 65536
  float* bc     = Wc + 65536;          // 256
  float* wc2    = bc + 256;            // 256
  float* cconst = wc2 + 256;           // (64 pad)  == proven 202.4MB footprint

  hipLaunchKernelGGL(k0_prep, dim3(257), dim3(256), 0, stream,
                     Wqkv, bqkv, Wmlp, bmlp, Wc, bc, wc2, cconst);
  hipLaunchKernelGGL(k_qbase, dim3(512), dim3(256), 0, stream,
                     emb, Wfix, bfix, Wstep, bstep, qbase);
  hipLaunchKernelGGL(k_c, dim3(256), dim3(256), 0, stream,
                     emb, wc2, cconst, cvec);
  hipLaunchKernelGGL(k_gemm, dim3(1024), dim3(256), 0, stream,
                     emb, Wqkv, bqkv, Wstep, Wc, bc, qbase, kk_, sqp, lkp);
  hipLaunchKernelGGL(k_roll, dim3(512), dim3(512), 0, stream,
                     emb, Wqkv, bqkv, kk_, sqp, lkp, cvec, out);
}

// Round 11
// 1376.840 us; speedup vs baseline: 1.7397x; 1.7397x over previous
//
#include <hip/hip_runtime.h>
#include <math.h>

// B=512, N=128, E=256, H=8, D=32. All fp32 (argmax fidelity requires it).
//
// Round-11: R8 kernel + amdgpu_waves_per_eu(2,2) on k_roll.
//  The allocator grants 65536/block_size VGPRs because it TARGETS 2 blocks/CU;
//  launch_bounds(512,1) only raises the cap, not the target. waves_per_eu max=2
//  forces the target to 2 waves/EU -> 256 VGPR/wave budget; occupancy unchanged
//  (LDS already caps at 1 block/CU = 8 waves). K/V/L (192 pinned floats) can
//  finally be resident. Everything else identical to R8.

#define B_ 512
#define N_ 128
#define E_ 256
#define NEG (-1.0e9f)
#define CLIPV 10.0f
#define SCALE 0.17677669529663688110f  /* 1/sqrt(32), fp32-rounded */

#define REP8(M) M(0) M(1) M(2) M(3) M(4) M(5) M(6) M(7)
#define REP16(M) REP8(M) M(8) M(9) M(10) M(11) M(12) M(13) M(14) M(15)
#define DOT4(a,b) ((a).x*(b).x + (a).y*(b).y + (a).z*(b).z + (a).w*(b).w)

__device__ __forceinline__ void fma4(float4& d, float a, float4 b) {
  d.x += a * b.x; d.y += a * b.y; d.z += a * b.z; d.w += a * b.w;
}
__device__ __forceinline__ float4 add4(float4 a, float4 b) {
  return make_float4(a.x + b.x, a.y + b.y, a.z + b.z, a.w + b.w);
}

// ---------------- wave-wide reductions (64 lanes) ----------------
template <int CTRL>
__device__ __forceinline__ float dpp_f(float x) {
  int r = __builtin_amdgcn_update_dpp(__float_as_int(x), __float_as_int(x),
                                      CTRL, 0xf, 0xf, false);
  return __int_as_float(r);
}
__device__ __forceinline__ float wred_max(float v) {
  v = fmaxf(v, dpp_f<0xB1>(v));
  v = fmaxf(v, dpp_f<0x4E>(v));
  v = fmaxf(v, dpp_f<0x124>(v));
  v = fmaxf(v, dpp_f<0x128>(v));
  v = fmaxf(v, __shfl_xor(v, 16));
  v = fmaxf(v, __shfl_xor(v, 32));
  return v;
}
__device__ __forceinline__ float wred_sum(float v) {
  v += dpp_f<0xB1>(v);
  v += dpp_f<0x4E>(v);
  v += dpp_f<0x124>(v);
  v += dpp_f<0x128>(v);
  v += __shfl_xor(v, 16);
  v += __shfl_xor(v, 32);
  return v;
}

// ---------------------------------------------------------------- K0: weight folds
__global__ void k0_prep(const float* __restrict__ Wqkv, const float* __restrict__ bqkv,
                        const float* __restrict__ Wmlp, const float* __restrict__ bmlp,
                        float* __restrict__ Wc, float* __restrict__ bc,
                        float* __restrict__ wc2, float* __restrict__ cconst) {
  int t = threadIdx.x;
  int blk = blockIdx.x;
  __shared__ float row_s[E_];
  if (blk < E_) {
    int g = blk;
    row_s[t] = Wqkv[g * 768 + 512 + t];
    __syncthreads();
    int f = t;
    const float4* wm4 = (const float4*)(Wmlp + f * E_);
    const float4* w34 = (const float4*)row_s;
    float acc = 0.f;
#pragma unroll 8
    for (int j = 0; j < E_ / 4; ++j) {
      float4 a = w34[j]; float4 bv = wm4[j];
      acc += a.x * bv.x + a.y * bv.y + a.z * bv.z + a.w * bv.w;
    }
    Wc[g * E_ + f] = acc;
  } else {
    int f = t;
    float a1 = 0.f, a2 = 0.f;
    for (int e = 0; e < E_; ++e) {
      a1 += bqkv[512 + e] * Wmlp[f * E_ + e];
      a2 += Wqkv[f * 768 + 512 + e] * bmlp[e];
    }
    bc[f] = a1;
    wc2[f] = a2;
    if (t == 0) {
      float c = 0.f;
      for (int e = 0; e < E_; ++e) c += bqkv[512 + e] * bmlp[e];
      *cconst = c;
    }
  }
}

// ---------------------------------------------------------------- K1: precompute GEMM (3 tensors)
// tmask bit (cc>>1): store that tensor transposed per b as out[b][e][n].
__global__ __launch_bounds__(256, 2)
void k_gemm(const float* __restrict__ emb, const float* __restrict__ Wqkv,
            const float* __restrict__ bqkv,
            const float* __restrict__ Wc, const float* __restrict__ bc,
            float* __restrict__ kk_, float* __restrict__ vv_,
            float* __restrict__ lk2, int ncc, int tmask) {
  __shared__ float As[256 * 64];  // [kk][m], exactly 64 KiB
  int t = threadIdx.x;
  int r0 = blockIdx.x * 64;
  {
    int m = t >> 2;
    int c0 = t & 3;
    const float4* e4 = (const float4*)emb;
#pragma unroll
    for (int p = 0; p < 16; ++p) {
      int c4 = c0 + p * 4;
      float4 a = e4[(size_t)(r0 + m) * 64 + c4];
      As[(c4 * 4 + 0) * 64 + m] = a.x;
      As[(c4 * 4 + 1) * 64 + m] = a.y;
      As[(c4 * 4 + 2) * 64 + m] = a.z;
      As[(c4 * 4 + 3) * 64 + m] = a.w;
    }
  }
  __syncthreads();
  int tx = t & 15, ty = t >> 4;
  const float4* As4 = (const float4*)As;
  for (int cc = 0; cc < ncc; ++cc) {
    const float* Bp; int ldb4; const float* bias; float* outp;
    int colbase = (cc & 1) * 128;
    switch (cc >> 1) {
      case 0:  Bp = Wqkv + colbase;          ldb4 = 192; bias = bqkv + colbase;       outp = kk_; break;
      case 1:  Bp = Wqkv + 256 + colbase;    ldb4 = 192; bias = bqkv + 256 + colbase; outp = vv_; break;
      default: Bp = Wc + colbase;            ldb4 = 64;  bias = bc + colbase;         outp = lk2; break;
    }
    const float4* B4 = (const float4*)Bp;
    float acc[4][8];
#pragma unroll
    for (int i = 0; i < 4; ++i)
#pragma unroll
      for (int j = 0; j < 8; ++j) acc[i][j] = 0.f;

#pragma unroll 4
    for (int kk = 0; kk < 256; ++kk) {
      float4 b0 = B4[kk * ldb4 + tx * 2];
      float4 b1 = B4[kk * ldb4 + tx * 2 + 1];
      float4 av = As4[kk * 16 + ty];
      float a_[4] = {av.x, av.y, av.z, av.w};
#pragma unroll
      for (int i = 0; i < 4; ++i) {
        acc[i][0] += a_[i] * b0.x; acc[i][1] += a_[i] * b0.y;
        acc[i][2] += a_[i] * b0.z; acc[i][3] += a_[i] * b0.w;
        acc[i][4] += a_[i] * b1.x; acc[i][5] += a_[i] * b1.y;
        acc[i][6] += a_[i] * b1.z; acc[i][7] += a_[i] * b1.w;
      }
    }
    float bj[8];
#pragma unroll
    for (int j = 0; j < 8; ++j) bj[j] = bias ? bias[tx * 8 + j] : 0.f;
    int tr = (tmask >> (cc >> 1)) & 1;
    if (!tr) {
#pragma unroll
      for (int i = 0; i < 4; ++i) {
        int row = r0 + ty * 4 + i;
        float4 o0 = make_float4(acc[i][0] + bj[0], acc[i][1] + bj[1], acc[i][2] + bj[2], acc[i][3] + bj[3]);
        float4 o1 = make_float4(acc[i][4] + bj[4], acc[i][5] + bj[5], acc[i][6] + bj[6], acc[i][7] + bj[7]);
        float4* o4 = (float4*)(outp + (size_t)row * 256 + colbase + tx * 8);
        o4[0] = o0; o4[1] = o1;
      }
    } else {
#pragma unroll
      for (int i = 0; i < 4; ++i) {
        int row = r0 + ty * 4 + i;
        int bb = row >> 7, nn = row & 127;
        float* op = outp + (size_t)bb * 32768 + nn;
#pragma unroll
        for (int j = 0; j < 8; ++j)
          op[(size_t)(colbase + tx * 8 + j) * 128] = acc[i][j] + bj[j];
      }
    }
  }
}

// ---------------------------------------------------------------- K2: qbase per b
__global__ void k_qbase(const float* __restrict__ emb, const float* __restrict__ Wfix,
                        const float* __restrict__ bfix, const float* __restrict__ Wstep,
                        const float* __restrict__ bstep, float* __restrict__ qbase) {
  int b = blockIdx.x, t = threadIdx.x;
  __shared__ float ge[E_], fi[E_];
  const float* eb = emb + (size_t)b * N_ * E_;
  float s = 0.f;
#pragma unroll 8
  for (int n = 0; n < N_; ++n) s += eb[n * E_ + t];
  ge[t] = s * (1.0f / 128.0f);
  fi[t] = eb[t];
  __syncthreads();
  float acc = bfix[t] + bstep[t];
#pragma unroll 4
  for (int g = 0; g < E_; ++g)
    acc += ge[g] * Wfix[g * E_ + t] + fi[g] * Wstep[g * E_ + t];
  qbase[b * E_ + t] = acc;
}

// ---------------------------------------------------------------- K3: c[b,n]
__global__ void k_c(const float* __restrict__ emb, const float* __restrict__ wc2,
                    const float* __restrict__ cconst, float* __restrict__ cvec) {
  __shared__ float w[E_];
  int t = threadIdx.x;
  w[t] = wc2[t];
  __syncthreads();
  int row = blockIdx.x * 256 + t;
  const float4* e4 = (const float4*)(emb + (size_t)row * E_);
  const float4* w4 = (const float4*)w;
  float acc = 0.f;
#pragma unroll 8
  for (int j = 0; j < E_ / 4; ++j) {
    float4 a = e4[j], bv = w4[j];
    acc += a.x * bv.x + a.y * bv.y + a.z * bv.z + a.w * bv.w;
  }
  cvec[row] = acc + *cconst;
}

// ---------------------------------------------------------------- K4: wave-per-head rollout
// One block (512 thr, 8 waves) per batch element. Wave h == head h.
// amdgpu_waves_per_eu(2,2): force the register allocator to budget for 2 waves/EU
// (256 VGPR/wave) -- occupancy is LDS-capped at 8 waves/CU anyway.
__global__
__attribute__((amdgpu_flat_work_group_size(512, 512)))
__attribute__((amdgpu_waves_per_eu(2, 2)))
void k_roll(const float* __restrict__ emb, const float* __restrict__ Wstep,
            const float* __restrict__ kk, const float* __restrict__ vT,
            const float* __restrict__ lk,
            const float* __restrict__ qbase, const float* __restrict__ cvec,
            float* __restrict__ out) {
  int lt = threadIdx.x;
  int b = blockIdx.x;
  int h = lt >> 6;      // wave = head
  int j = lt & 63;      // lane

  __shared__ float sq_lds[128 * 260];   // 130 KiB
  __shared__ float work[6144];          // 24 KiB overlay: init At/Bs | at_s/ctx_s/zp
  float* at_s  = work;                  // [8][128] wave-private slices
  float* ctx_s = work + 1024;           // [8][32]  wave-private slices
  float* zp    = work + 1280;           // [2][8][128] double-buffered

  // ---- init: sq_lds[n][e] = qbase[b][e] + sum_g emb[b][n][g] * Wstep[256+g][e]
  {
    float* At = work;           // [16][128]
    float* Bs = work + 2048;    // [16][256]
    const float4* eb4 = (const float4*)(emb + (size_t)b * 32768);
    const float* W2 = Wstep + 65536;
    int n0 = (lt & 31) * 4;
    int e0 = (lt >> 5) * 16;
    float4 z4 = make_float4(0.f, 0.f, 0.f, 0.f);
#define DECAC(i) float4 ac##i##_0=z4, ac##i##_1=z4, ac##i##_2=z4, ac##i##_3=z4;
    DECAC(0) DECAC(1) DECAC(2) DECAC(3)

    for (int gc = 0; gc < 16; ++gc) {
      {
        int n = lt & 127, q4g = lt >> 7;
        float4 a = eb4[n * 64 + gc * 4 + q4g];
        At[(q4g * 4 + 0) * 128 + n] = a.x;
        At[(q4g * 4 + 1) * 128 + n] = a.y;
        At[(q4g * 4 + 2) * 128 + n] = a.z;
        At[(q4g * 4 + 3) * 128 + n] = a.w;
      }
      {
        const float4* w4 = (const float4*)(W2 + gc * 16 * 256);
        ((float4*)Bs)[lt] = w4[lt];
        ((float4*)Bs)[lt + 512] = w4[lt + 512];
      }
      __syncthreads();
#pragma unroll
      for (int gi = 0; gi < 16; ++gi) {
        float4 a4v = *(const float4*)(At + gi * 128 + n0);
        const float4* bp = (const float4*)(Bs + gi * 256 + e0);
        float4 b0 = bp[0], b1 = bp[1], b2 = bp[2], b3 = bp[3];
#define ACU(i, comp) fma4(ac##i##_0, a4v.comp, b0); fma4(ac##i##_1, a4v.comp, b1); \
                     fma4(ac##i##_2, a4v.comp, b2); fma4(ac##i##_3, a4v.comp, b3);
        ACU(0, x) ACU(1, y) ACU(2, z) ACU(3, w)
      }
      __syncthreads();
    }
    const float4* qb4 = (const float4*)(qbase + (size_t)b * 256 + e0);
    float4 qb0 = qb4[0], qb1 = qb4[1], qb2 = qb4[2], qb3 = qb4[3];
#define STO(i) \
    *(float4*)(sq_lds + (n0 + (i)) * 260 + e0 + 0)  = add4(ac##i##_0, qb0); \
    *(float4*)(sq_lds + (n0 + (i)) * 260 + e0 + 4)  = add4(ac##i##_1, qb1); \
    *(float4*)(sq_lds + (n0 + (i)) * 260 + e0 + 8)  = add4(ac##i##_2, qb2); \
    *(float4*)(sq_lds + (n0 + (i)) * 260 + e0 + 12) = add4(ac##i##_3, qb3);
    STO(0) STO(1) STO(2) STO(3)
  }
  __syncthreads();

  // ---- register fills: named float4 values, contiguous global float4 loads ----
  const float4* kb4 = (const float4*)(kk + (size_t)b * 32768);
  const float4* vb4 = (const float4*)(vT + (size_t)b * 32768);
  const float4* lb4 = (const float4*)(lk + (size_t)b * 32768);
  int e_own = h * 32 + (j & 31), nh = j >> 5;
  int row0 = j * 64 + h * 8;          // k/lk2 row n=j, head slice (float4 idx)
  int row1 = (j + 64) * 64 + h * 8;   // row n=j+64
  int vrow = e_own * 32 + nh * 16;    // vT row e_own, n-half (float4 idx)

#define DKL(i) float4 K0_##i = kb4[row0 + (i)], K1_##i = kb4[row1 + (i)], \
                      L0_##i = lb4[row0 + (i)], L1_##i = lb4[row1 + (i)];
  REP8(DKL)
#define DV(i) float4 V_##i = vb4[vrow + (i)];
  REP16(DV)

  // ---- PIN: values become opaque asm results -> cannot be remat'd/sunk ----
#define PIN4(v) asm volatile("" : "+v"((v).x), "+v"((v).y), "+v"((v).z), "+v"((v).w));
#define PINKL(i) PIN4(K0_##i) PIN4(K1_##i) PIN4(L0_##i) PIN4(L1_##i)
  REP8(PINKL)
#define PINV(i) PIN4(V_##i)
  REP16(PINV)

  float cv_lo = cvec[b * 128 + j];
  float cv_hi = cvec[b * 128 + j + 64];
  int vis_lo = (j == 0) ? 1 : 0, vis_hi = 0;
  int cur = 0;
  float lp = 0.f;

#pragma unroll 1
  for (int it = 0; it < N_ - 1; ++it) {
    // --- scores (wave-local; q row broadcast-read from sq_lds) ---
    const float4* q4 = (const float4*)(sq_lds + cur * 260 + h * 32);
    float sa0 = 0.f, sb0 = 0.f, sa1 = 0.f, sb1 = 0.f;
#define SCM(i) { float4 qv = q4[(i)]; \
      if ((i) & 1) { sb0 += DOT4(qv, K0_##i); sb1 += DOT4(qv, K1_##i); } \
      else         { sa0 += DOT4(qv, K0_##i); sa1 += DOT4(qv, K1_##i); } }
    REP8(SCM)
    float slo = vis_lo ? NEG : (sa0 + sb0) * SCALE;
    float shi = vis_hi ? NEG : (sa1 + sb1) * SCALE;
    // --- softmax (in-wave; division deferred to ctx scaling) ---
    float m = wred_max(fmaxf(slo, shi));
    float elo = expf(slo - m), ehi = expf(shi - m);
    at_s[h * 128 + j] = elo;
    at_s[h * 128 + 64 + j] = ehi;
    float inv = 1.0f / wred_sum(elo + ehi);
    // --- ctx for e_own over n-half (wave-local LDS read, no barrier) ---
    const float4* a4 = (const float4*)(at_s + h * 128 + nh * 64);
    float c0 = 0.f, c1 = 0.f;
#define CTM(i) { float4 av = a4[(i)]; \
      if ((i) & 1) c1 += DOT4(av, V_##i); else c0 += DOT4(av, V_##i); }
    REP16(CTM)
    float c = c0 + c1;
    c += __shfl_xor(c, 32);     // combine n-halves (lanes j, j^32 share e_own)
    c *= inv;
    if (j < 32) ctx_s[h * 32 + j] = c;
    // --- z partial for head-slice (wave-local broadcast read) ---
    const float4* cx4 = (const float4*)(ctx_s + h * 32);
    float z0a = 0.f, z0b = 0.f, z1a = 0.f, z1b = 0.f;
#define ZPM(i) { float4 cv = cx4[(i)]; \
      if ((i) & 1) { z0b += DOT4(cv, L0_##i); z1b += DOT4(cv, L1_##i); } \
      else         { z0a += DOT4(cv, L0_##i); z1a += DOT4(cv, L1_##i); } }
    REP8(ZPM)
    float* zpw = zp + (it & 1) * 1024;
    zpw[h * 128 + j] = z0a + z0b;
    zpw[h * 128 + 64 + j] = z1a + z1b;
    __syncthreads();   // the ONLY barrier per step

    // --- phase C: every wave redundantly assembles z, argmax (ballot), lse ---
    float zlo = cv_lo, zhi = cv_hi;
#pragma unroll
    for (int hh = 0; hh < 8; ++hh) {
      zlo += zpw[hh * 128 + j];
      zhi += zpw[hh * 128 + 64 + j];
    }
    float zmlo = vis_lo ? -1e30f : zlo;
    float zmhi = vis_hi ? -1e30f : zhi;
    float vmax = wred_max(fmaxf(zmlo, zmhi));
    unsigned long long blo = __ballot(zmlo == vmax);
    int action;
    if (blo) action = __ffsll((unsigned long long)blo) - 1;
    else     action = 63 + __ffsll((unsigned long long)__ballot(zmhi == vmax));
    float lmax = CLIPV * tanhf(vmax * SCALE);
    float tlo = vis_lo ? 0.f : expf(CLIPV * tanhf(zlo * SCALE) - 10.0f);
    float thi = vis_hi ? 0.f : expf(CLIPV * tanhf(zhi * SCALE) - 10.0f);
    float S = wred_sum(tlo + thi);
    lp += lmax - 10.0f - logf(S);
    cur = action;
    vis_lo |= (action == j);
    vis_hi |= (action == j + 64);
  }
  if (lt == 0) out[b] = lp;
}

// ---------------------------------------------------------------- launch
extern "C" void kernel_launch(void* const* d_in, const int* in_sizes, int n_in,
                              void* d_out, int out_size, void* d_ws, size_t ws_size,
                              hipStream_t stream) {
  (void)in_sizes; (void)n_in; (void)out_size; (void)ws_size;
  const float* emb   = (const float*)d_in[0];
  const float* Wqkv  = (const float*)d_in[1];
  const float* bqkv  = (const float*)d_in[2];
  const float* Wfix  = (const float*)d_in[3];
  const float* bfix  = (const float*)d_in[4];
  const float* Wstep = (const float*)d_in[5];
  const float* bstep = (const float*)d_in[6];
  const float* Wmlp  = (const float*)d_in[7];
  const float* bmlp  = (const float*)d_in[8];
  float* out = (float*)d_out;
  float* ws = (float*)d_ws;

  const size_t NBE = (size_t)B_ * N_ * E_;  // 16,777,216 floats
  float* kk_    = ws;                  // k   (untransposed)
  float* vv_    = ws + NBE;            // vT  (transposed per b)
  float* lk2    = ws + 2 * NBE;        // lk2 (untransposed)
  float* qbase  = ws + 3 * NBE;        // 131072
  float* cvec   = qbase + 131072;      // 65536
  float* Wc     = cvec + 65536;        // 65536
  float* bc     = Wc + 65536;          // 256
  float* wc2    = bc + 256;            // 256
  float* cconst = wc2 + 256;           // (64 pad)

  hipLaunchKernelGGL(k0_prep, dim3(257), dim3(256), 0, stream,
                     Wqkv, bqkv, Wmlp, bmlp, Wc, bc, wc2, cconst);
  hipLaunchKernelGGL(k_qbase, dim3(512), dim3(256), 0, stream,
                     emb, Wfix, bfix, Wstep, bstep, qbase);
  hipLaunchKernelGGL(k_c, dim3(256), dim3(256), 0, stream,
                     emb, wc2, cconst, cvec);
  hipLaunchKernelGGL(k_gemm, dim3(1024), dim3(256), 0, stream,
                     emb, Wqkv, bqkv, Wc, bc, kk_, vv_, lk2, 6, 0b010);
  hipLaunchKernelGGL(k_roll, dim3(512), dim3(512), 0, stream,
                     emb, Wstep, kk_, vv_, lk2, qbase, cvec, out);
}